// Round 1
// baseline (8635.783 us; speedup 1.0000x reference)
//
#include <hip/hip_runtime.h>
#include <cstdint>

#define D 128

// ---------------------------------------------------------------- kernels

__global__ void k_count(const int* __restrict__ src, const int* __restrict__ dst,
                        int E, float* __restrict__ degs, float* __restrict__ degd) {
    int i = blockIdx.x * blockDim.x + threadIdx.x;
    if (i < E) {
        atomicAdd(&degs[src[i]], 1.0f);
        atomicAdd(&degd[dst[i]], 1.0f);
    }
}

__global__ void k_rsqrt(float* __restrict__ p, int n) {
    int i = blockIdx.x * blockDim.x + threadIdx.x;
    if (i < n) {
        float d = p[i];
        p[i] = d > 0.0f ? rsqrtf(d) : 0.0f;
    }
}

// m[dst[e]][c] += x[src[e]][c] * ns[src[e]]   (thread = edge x 4 channels)
__global__ void k_scatter(const float* __restrict__ x, const float* __restrict__ ns,
                          const int* __restrict__ src, const int* __restrict__ dst,
                          int E, float* __restrict__ m) {
    int gid = blockIdx.x * blockDim.x + threadIdx.x;
    int e = gid >> 5;
    if (e >= E) return;
    int c = (gid & 31) * 4;
    int s = src[e];
    int d = dst[e];
    float w = ns[s];
    float4 v = *(const float4*)(x + (size_t)s * D + c);
    float* mp = m + (size_t)d * D + c;
    atomicAdd(mp + 0, v.x * w);
    atomicAdd(mp + 1, v.y * w);
    atomicAdd(mp + 2, v.z * w);
    atomicAdd(mp + 3, v.w * w);
}

// In-place: m[r][:] = (m[r][:] @ W) * nd[r]; accumulates channel sum/sumsq into stats[256].
// Block 256 threads. LDS: W half-K 64x128 (32KB) + M chunk 32x128 (16KB) + stats (1KB).
__global__ __launch_bounds__(256) void k_gemm_stats(
    float* __restrict__ m, const float* __restrict__ W,
    const float* __restrict__ nd, int n, float* __restrict__ stats) {
    __shared__ float Wl[64 * 128];
    __shared__ float Ml[32 * 128];
    __shared__ float Sl[256];
    int t = threadIdx.x;
    Sl[t] = 0.0f;
    int c4 = (t & 31) * 4;
    int rg = t >> 5;   // 0..7, rows rg*4 .. rg*4+3

    for (int r0 = blockIdx.x * 32; r0 < n; r0 += gridDim.x * 32) {
        __syncthreads();   // previous chunk's LDS readers done
        int rows = min(32, n - r0);
        {
            const float4* gm = (const float4*)(m + (size_t)r0 * D);
            for (int i = t; i < rows * 32; i += 256) ((float4*)Ml)[i] = gm[i];
        }
        float acc[4][4] = {};
        for (int half = 0; half < 2; ++half) {
            __syncthreads();   // half0: Ml ready-gate; half1: Wl readers done
            {
                const float4* gw = (const float4*)(W + half * 64 * D);
                for (int i = t; i < 64 * 32; i += 256) ((float4*)Wl)[i] = gw[i];
            }
            __syncthreads();   // Wl ready
            #pragma unroll 4
            for (int k0 = 0; k0 < 64; k0 += 4) {
                float4 w0 = *(float4*)(Wl + (k0 + 0) * D + c4);
                float4 w1 = *(float4*)(Wl + (k0 + 1) * D + c4);
                float4 w2 = *(float4*)(Wl + (k0 + 2) * D + c4);
                float4 w3 = *(float4*)(Wl + (k0 + 3) * D + c4);
                #pragma unroll
                for (int j = 0; j < 4; ++j) {
                    float4 mm = *(float4*)(Ml + (rg * 4 + j) * D + half * 64 + k0);
                    acc[j][0] += mm.x * w0.x + mm.y * w1.x + mm.z * w2.x + mm.w * w3.x;
                    acc[j][1] += mm.x * w0.y + mm.y * w1.y + mm.z * w2.y + mm.w * w3.y;
                    acc[j][2] += mm.x * w0.z + mm.y * w1.z + mm.z * w2.z + mm.w * w3.z;
                    acc[j][3] += mm.x * w0.w + mm.y * w1.w + mm.z * w2.w + mm.w * w3.w;
                }
            }
        }
        #pragma unroll
        for (int j = 0; j < 4; ++j) {
            int r = rg * 4 + j;
            if (r < rows) {
                float s = nd[r0 + r];
                float4 o;
                o.x = acc[j][0] * s; o.y = acc[j][1] * s;
                o.z = acc[j][2] * s; o.w = acc[j][3] * s;
                *(float4*)(m + (size_t)(r0 + r) * D + c4) = o;
                atomicAdd(&Sl[c4 + 0], o.x);
                atomicAdd(&Sl[c4 + 1], o.y);
                atomicAdd(&Sl[c4 + 2], o.z);
                atomicAdd(&Sl[c4 + 3], o.w);
                atomicAdd(&Sl[128 + c4 + 0], o.x * o.x);
                atomicAdd(&Sl[128 + c4 + 1], o.y * o.y);
                atomicAdd(&Sl[128 + c4 + 2], o.z * o.z);
                atomicAdd(&Sl[128 + c4 + 3], o.w * o.w);
            }
        }
    }
    __syncthreads();
    atomicAdd(&stats[t], Sl[t]);
}

// BN normalize + store/accumulate. mode 0: dst = v; mode 1: dst += v; mode 2: dst = v + resid
__global__ void k_norm(const float4* __restrict__ out4, const float* __restrict__ stats,
                       const float* __restrict__ gamma, const float* __restrict__ beta,
                       float inv_n, long total4, float4* __restrict__ dst4,
                       const float4* __restrict__ resid4, int mode) {
    __shared__ float sc[128], sh[128];
    int t = threadIdx.x;
    if (t < 128) {
        float mu = stats[t] * inv_n;
        float var = stats[128 + t] * inv_n - mu * mu;
        float s = gamma[t] * rsqrtf(var + 1e-5f);
        sc[t] = s;
        sh[t] = beta[t] - mu * s;
    }
    __syncthreads();
    for (long i = (long)blockIdx.x * blockDim.x + t; i < total4;
         i += (long)gridDim.x * blockDim.x) {
        int c4 = ((int)i & 31) * 4;
        float4 v = out4[i];
        float4 r;
        r.x = v.x * sc[c4 + 0] + sh[c4 + 0];
        r.y = v.y * sc[c4 + 1] + sh[c4 + 1];
        r.z = v.z * sc[c4 + 2] + sh[c4 + 2];
        r.w = v.w * sc[c4 + 3] + sh[c4 + 3];
        if (mode == 1) {
            float4 d = dst4[i];
            r.x += d.x; r.y += d.y; r.z += d.z; r.w += d.w;
        } else if (mode == 2) {
            float4 d = resid4[i];
            r.x += d.x; r.y += d.y; r.z += d.z; r.w += d.w;
        }
        dst4[i] = r;
    }
}

// ---------------------------------------------------------------- launch

extern "C" void kernel_launch(void* const* d_in, const int* in_sizes, int n_in,
                              void* d_out, int out_size, void* d_ws, size_t ws_size,
                              hipStream_t stream) {
    static const int NT[3]   = {100000, 150000, 2000};
    static const int RE[9]   = {300000, 300000, 100000, 100000, 150000, 150000, 100000, 150000, 2000};
    static const int RSRC[9] = {0, 1, 0, 2, 1, 2, 0, 1, 2};
    static const int RDST[9] = {1, 0, 2, 0, 2, 1, 0, 1, 2};

    const float* feat_in[3] = {(const float*)d_in[0], (const float*)d_in[1], (const float*)d_in[2]};
    const float* W     = (const float*)d_in[3];
    const float* gamma = (const float*)d_in[5];
    const float* beta  = (const float*)d_in[6];
    float* ws  = (float*)d_ws;
    float* out = (float*)d_out;

    // workspace layout (floats)
    const size_t F_A = 0;                      // 100000*128
    const size_t F_B = F_A + 12800000;         // 150000*128
    const size_t F_G = F_B + 19200000;         // 2000*128
    const size_t MBUF = F_G + 256000;          // 150000*128
    const size_t STATS = MBUF + 19200000;      // 256
    const size_t DEGS = STATS + 256;           // 1,512,000

    float* ws_feat[3]  = {ws + F_A, ws + F_B, ws + F_G};
    float* out_feat[3] = {out, out + 12800000, out + 32000000};
    float* mbuf  = ws + MBUF;
    float* stats = ws + STATS;

    // degree offsets per relation
    size_t deg_ns[9], deg_nd[9];
    {
        size_t off = DEGS;
        for (int r = 0; r < 9; ++r) {
            deg_ns[r] = off;
            deg_nd[r] = off + (size_t)NT[RSRC[r]];
            off += (size_t)NT[RSRC[r]] + (size_t)NT[RDST[r]];
        }
        hipMemsetAsync(ws + DEGS, 0, (off - DEGS) * sizeof(float), stream);
    }

    // degree counts + rsqrt transform (edges are layer-independent)
    for (int r = 0; r < 9; ++r) {
        const int* src = (const int*)d_in[7 + 2 * r];
        const int* dst = (const int*)d_in[8 + 2 * r];
        int E = RE[r];
        k_count<<<(E + 255) / 256, 256, 0, stream>>>(src, dst, E, ws + deg_ns[r], ws + deg_nd[r]);
    }
    k_rsqrt<<<(1512000 + 255) / 256, 256, 0, stream>>>(ws + DEGS, 1512000);

    for (int l = 0; l < 2; ++l) {
        bool touched[3] = {false, false, false};
        for (int r = 0; r < 9; ++r) {
            const int* src = (const int*)d_in[7 + 2 * r];
            const int* dst = (const int*)d_in[8 + 2 * r];
            int E = RE[r];
            int st = RSRC[r], dt = RDST[r];
            int n_dst = NT[dt];
            const float* x = (l == 0) ? feat_in[st] : (const float*)ws_feat[st];

            hipMemsetAsync(mbuf, 0, (size_t)n_dst * D * sizeof(float), stream);
            k_scatter<<<((size_t)E * 32 + 255) / 256, 256, 0, stream>>>(
                x, ws + deg_ns[r], src, dst, E, mbuf);

            hipMemsetAsync(stats, 0, 256 * sizeof(float), stream);
            int chunks = (n_dst + 31) / 32;
            int ggrid = chunks < 768 ? chunks : 768;
            k_gemm_stats<<<ggrid, 256, 0, stream>>>(
                mbuf, W + (size_t)(l * 9 + r) * D * D, ws + deg_nd[r], n_dst, stats);

            // mode: first touch of dst-type this layer -> store (layer0) / store+resid (layer1)
            int mode = touched[dt] ? 1 : (l == 0 ? 0 : 2);
            float* dbuf = (l == 0) ? ws_feat[dt] : out_feat[dt];
            long total4 = (long)n_dst * (D / 4);
            int ngrid = (int)((total4 + 255) / 256);
            if (ngrid > 2048) ngrid = 2048;
            k_norm<<<ngrid, 256, 0, stream>>>(
                (const float4*)mbuf, stats,
                gamma + (size_t)(l * 9 + r) * D, beta + (size_t)(l * 9 + r) * D,
                1.0f / (float)n_dst, total4, (float4*)dbuf,
                (const float4*)feat_in[dt], mode);
            touched[dt] = true;
        }
    }
}

// Round 2
// 4650.384 us; speedup vs baseline: 1.8570x; 1.8570x over previous
//
#include <hip/hip_runtime.h>
#include <cstdint>

#define D 128

// ---------------------------------------------------------------- degree / CSR build

__global__ void k_count(const int* __restrict__ src, const int* __restrict__ dst,
                        int E, float* __restrict__ degs, float* __restrict__ degd) {
    int i = blockIdx.x * blockDim.x + threadIdx.x;
    if (i < E) {
        atomicAdd(&degs[src[i]], 1.0f);
        atomicAdd(&degd[dst[i]], 1.0f);
    }
}

__global__ void k_rsqrt(float* __restrict__ p, int n) {
    int i = blockIdx.x * blockDim.x + threadIdx.x;
    if (i < n) {
        float d = p[i];
        p[i] = d > 0.0f ? rsqrtf(d) : 0.0f;
    }
}

// block-level inclusive scan -> exclusive offsets + per-block totals
__global__ void k_scan1(const float* __restrict__ cnt, int* __restrict__ off,
                        int* __restrict__ bsum, int n) {
    __shared__ int s[256];
    int t = threadIdx.x, i = blockIdx.x * 256 + t;
    int v = (i < n) ? (int)cnt[i] : 0;
    int acc = v;
    s[t] = acc; __syncthreads();
    for (int d = 1; d < 256; d <<= 1) {
        int add = (t >= d) ? s[t - d] : 0;
        __syncthreads();
        acc += add; s[t] = acc; __syncthreads();
    }
    if (i < n) off[i] = acc - v;          // exclusive
    if (t == 255) bsum[blockIdx.x] = acc; // block total
}

// single-block exclusive scan of block totals (nb <= 3072)
__global__ __launch_bounds__(1024) void k_scan2(int* __restrict__ bsum, int nb) {
    __shared__ int s[1024];
    int t = threadIdx.x;
    int i0 = t * 3;
    int v0 = (i0     < nb) ? bsum[i0]     : 0;
    int v1 = (i0 + 1 < nb) ? bsum[i0 + 1] : 0;
    int v2 = (i0 + 2 < nb) ? bsum[i0 + 2] : 0;
    int tot = v0 + v1 + v2;
    int acc = tot;
    s[t] = acc; __syncthreads();
    for (int d = 1; d < 1024; d <<= 1) {
        int add = (t >= d) ? s[t - d] : 0;
        __syncthreads();
        acc += add; s[t] = acc; __syncthreads();
    }
    int base = acc - tot; // exclusive across threads
    if (i0     < nb) bsum[i0]     = base;
    if (i0 + 1 < nb) bsum[i0 + 1] = base + v0;
    if (i0 + 2 < nb) bsum[i0 + 2] = base + v0 + v1;
}

__global__ void k_scan3(int* __restrict__ off, const int* __restrict__ bsum, int n) {
    int i = blockIdx.x * 256 + threadIdx.x;
    if (i < n) off[i] += bsum[blockIdx.x];
}

// bucket edges by dst: offs is this relation's slice (exclusive scan values);
// after fill, offs[d] == inclusive end of row d.
__global__ void k_fill(const int* __restrict__ src, const int* __restrict__ dst,
                       int E, int* __restrict__ offs, int* __restrict__ sorted) {
    int e = blockIdx.x * blockDim.x + threadIdx.x;
    if (e < E) {
        int pos = atomicAdd(&offs[dst[e]], 1);
        sorted[pos] = src[e];
    }
}

// ---------------------------------------------------------------- aggregation (gather)

// 32 lanes per dst row, float4 per lane; one coalesced 512B write per row.
__global__ void k_gather(const float* __restrict__ x, const float* __restrict__ ns,
                         const int* __restrict__ OFFS, int gdbase,
                         const int* __restrict__ sorted, int n_dst,
                         float* __restrict__ m) {
    int gid = blockIdx.x * blockDim.x + threadIdx.x;
    int row = gid >> 5;
    if (row >= n_dst) return;
    int c4 = (gid & 31) * 4;
    int gd = gdbase + row;
    int beg = (gd == 0) ? 0 : OFFS[gd - 1];
    int end = OFFS[gd];
    float4 acc = {0.f, 0.f, 0.f, 0.f};
    for (int j = beg; j < end; ++j) {
        int s = sorted[j];
        float w = ns[s];
        float4 v = *(const float4*)(x + (size_t)s * D + c4);
        acc.x += v.x * w; acc.y += v.y * w; acc.z += v.z * w; acc.w += v.w * w;
    }
    *(float4*)(m + (size_t)row * D + c4) = acc;
}

// ---------------------------------------------------------------- GEMM + BN stats

// In-place: m[r][:] = (m[r][:] @ W) * nd[r]; accumulates channel sum/sumsq into stats[256].
__global__ __launch_bounds__(256) void k_gemm_stats(
    float* __restrict__ m, const float* __restrict__ W,
    const float* __restrict__ nd, int n, float* __restrict__ stats) {
    __shared__ float Wl[64 * 128];
    __shared__ float Ml[32 * 128];
    __shared__ float Sl[256];
    int t = threadIdx.x;
    Sl[t] = 0.0f;
    int c4 = (t & 31) * 4;
    int rg = t >> 5;   // 0..7, rows rg*4 .. rg*4+3

    for (int r0 = blockIdx.x * 32; r0 < n; r0 += gridDim.x * 32) {
        __syncthreads();   // previous chunk's LDS readers done
        int rows = min(32, n - r0);
        {
            const float4* gm = (const float4*)(m + (size_t)r0 * D);
            for (int i = t; i < rows * 32; i += 256) ((float4*)Ml)[i] = gm[i];
        }
        float acc[4][4] = {};
        for (int half = 0; half < 2; ++half) {
            __syncthreads();   // half0: Ml ready-gate; half1: Wl readers done
            {
                const float4* gw = (const float4*)(W + half * 64 * D);
                for (int i = t; i < 64 * 32; i += 256) ((float4*)Wl)[i] = gw[i];
            }
            __syncthreads();   // Wl ready
            #pragma unroll 4
            for (int k0 = 0; k0 < 64; k0 += 4) {
                float4 w0 = *(float4*)(Wl + (k0 + 0) * D + c4);
                float4 w1 = *(float4*)(Wl + (k0 + 1) * D + c4);
                float4 w2 = *(float4*)(Wl + (k0 + 2) * D + c4);
                float4 w3 = *(float4*)(Wl + (k0 + 3) * D + c4);
                #pragma unroll
                for (int j = 0; j < 4; ++j) {
                    float4 mm = *(float4*)(Ml + (rg * 4 + j) * D + half * 64 + k0);
                    acc[j][0] += mm.x * w0.x + mm.y * w1.x + mm.z * w2.x + mm.w * w3.x;
                    acc[j][1] += mm.x * w0.y + mm.y * w1.y + mm.z * w2.y + mm.w * w3.y;
                    acc[j][2] += mm.x * w0.z + mm.y * w1.z + mm.z * w2.z + mm.w * w3.z;
                    acc[j][3] += mm.x * w0.w + mm.y * w1.w + mm.z * w2.w + mm.w * w3.w;
                }
            }
        }
        #pragma unroll
        for (int j = 0; j < 4; ++j) {
            int r = rg * 4 + j;
            if (r < rows) {
                float s = nd[r0 + r];
                float4 o;
                o.x = acc[j][0] * s; o.y = acc[j][1] * s;
                o.z = acc[j][2] * s; o.w = acc[j][3] * s;
                *(float4*)(m + (size_t)(r0 + r) * D + c4) = o;
                atomicAdd(&Sl[c4 + 0], o.x);
                atomicAdd(&Sl[c4 + 1], o.y);
                atomicAdd(&Sl[c4 + 2], o.z);
                atomicAdd(&Sl[c4 + 3], o.w);
                atomicAdd(&Sl[128 + c4 + 0], o.x * o.x);
                atomicAdd(&Sl[128 + c4 + 1], o.y * o.y);
                atomicAdd(&Sl[128 + c4 + 2], o.z * o.z);
                atomicAdd(&Sl[128 + c4 + 3], o.w * o.w);
            }
        }
    }
    __syncthreads();
    atomicAdd(&stats[t], Sl[t]);
}

// ---------------------------------------------------------------- BN normalize + accumulate

// mode 0: dst = v; mode 1: dst += v; mode 2: dst = v + resid
__global__ void k_norm(const float4* __restrict__ out4, const float* __restrict__ stats,
                       const float* __restrict__ gamma, const float* __restrict__ beta,
                       float inv_n, long total4, float4* __restrict__ dst4,
                       const float4* __restrict__ resid4, int mode) {
    __shared__ float sc[128], sh[128];
    int t = threadIdx.x;
    if (t < 128) {
        float mu = stats[t] * inv_n;
        float var = stats[128 + t] * inv_n - mu * mu;
        float s = gamma[t] * rsqrtf(var + 1e-5f);
        sc[t] = s;
        sh[t] = beta[t] - mu * s;
    }
    __syncthreads();
    for (long i = (long)blockIdx.x * blockDim.x + t; i < total4;
         i += (long)gridDim.x * blockDim.x) {
        int c4 = ((int)i & 31) * 4;
        float4 v = out4[i];
        float4 r;
        r.x = v.x * sc[c4 + 0] + sh[c4 + 0];
        r.y = v.y * sc[c4 + 1] + sh[c4 + 1];
        r.z = v.z * sc[c4 + 2] + sh[c4 + 2];
        r.w = v.w * sc[c4 + 3] + sh[c4 + 3];
        if (mode == 1) {
            float4 d = dst4[i];
            r.x += d.x; r.y += d.y; r.z += d.z; r.w += d.w;
        } else if (mode == 2) {
            float4 d = resid4[i];
            r.x += d.x; r.y += d.y; r.z += d.z; r.w += d.w;
        }
        dst4[i] = r;
    }
}

// ---------------------------------------------------------------- launch

extern "C" void kernel_launch(void* const* d_in, const int* in_sizes, int n_in,
                              void* d_out, int out_size, void* d_ws, size_t ws_size,
                              hipStream_t stream) {
    static const int NT[3]   = {100000, 150000, 2000};
    static const int RE[9]   = {300000, 300000, 100000, 100000, 150000, 150000, 100000, 150000, 2000};
    static const int RSRC[9] = {0, 1, 0, 2, 1, 2, 0, 1, 2};
    static const int RDST[9] = {1, 0, 2, 0, 2, 1, 0, 1, 2};
    const int TOT_N = 756000;       // sum of n_src over rels == sum of n_dst over rels
    const int TOT_E = 1352000;
    const int NB = (TOT_N + 255) / 256;   // scan blocks = 2954

    const float* feat_in[3] = {(const float*)d_in[0], (const float*)d_in[1], (const float*)d_in[2]};
    const float* W     = (const float*)d_in[3];
    const float* gamma = (const float*)d_in[5];
    const float* beta  = (const float*)d_in[6];
    float* ws  = (float*)d_ws;
    float* out = (float*)d_out;

    // per-relation bases within NS / ND blocks
    int ns_base[9], nd_base[9];
    {
        int s = 0, d = 0;
        for (int r = 0; r < 9; ++r) {
            ns_base[r] = s; s += NT[RSRC[r]];
            nd_base[r] = d; d += NT[RDST[r]];
        }
    }

    // workspace layout (4-byte units)
    const size_t F_A    = 0;                        // 100000*128
    const size_t F_B    = F_A + 12800000;           // 150000*128
    const size_t F_G    = F_B + 19200000;           // 2000*128
    const size_t MBUF   = F_G + 256000;             // 150000*128
    const size_t STATS  = MBUF + 19200000;          // 18*256
    const size_t NS     = STATS + 4608;             // 756000 floats
    const size_t ND     = NS + 756000;              // 756000 floats
    const size_t OFFS   = ND + 756000;              // 756000 ints
    const size_t SORTED = OFFS + 756000;            // 1352000 ints
    const size_t BSUM   = SORTED + 1352000;         // 2954 ints

    float* ws_feat[3]  = {ws + F_A, ws + F_B, ws + F_G};
    float* out_feat[3] = {out, out + 12800000, out + 32000000};
    float* mbuf   = ws + MBUF;
    float* stats0 = ws + STATS;
    float* ns_blk = ws + NS;
    float* nd_blk = ws + ND;
    int*   offs   = (int*)(ws + OFFS);
    int*   sorted = (int*)(ws + SORTED);
    int*   bsum   = (int*)(ws + BSUM);

    // zero degree block + stats
    hipMemsetAsync(ws + STATS, 0, (4608 + 2 * 756000) * sizeof(float), stream);

    // 1) degree counts
    for (int r = 0; r < 9; ++r) {
        const int* src = (const int*)d_in[7 + 2 * r];
        const int* dst = (const int*)d_in[8 + 2 * r];
        k_count<<<(RE[r] + 255) / 256, 256, 0, stream>>>(
            src, dst, RE[r], ns_blk + ns_base[r], nd_blk + nd_base[r]);
    }
    // 2) global exclusive scan of concatenated in-degrees -> offsets
    k_scan1<<<NB, 256, 0, stream>>>(nd_blk, offs, bsum, TOT_N);
    k_scan2<<<1, 1024, 0, stream>>>(bsum, NB);
    k_scan3<<<NB, 256, 0, stream>>>(offs, bsum, TOT_N);
    // 3) bucket-fill sorted src lists (offs becomes inclusive ends)
    for (int r = 0; r < 9; ++r) {
        const int* src = (const int*)d_in[7 + 2 * r];
        const int* dst = (const int*)d_in[8 + 2 * r];
        k_fill<<<(RE[r] + 255) / 256, 256, 0, stream>>>(
            src, dst, RE[r], offs + nd_base[r], sorted);
    }
    // 4) degrees -> rsqrt norms
    k_rsqrt<<<(2 * TOT_N + 255) / 256, 256, 0, stream>>>(ns_blk, 2 * TOT_N);

    // 5) layers
    for (int l = 0; l < 2; ++l) {
        bool touched[3] = {false, false, false};
        for (int r = 0; r < 9; ++r) {
            int st = RSRC[r], dt = RDST[r];
            int n_dst = NT[dt];
            const float* x = (l == 0) ? feat_in[st] : (const float*)ws_feat[st];

            k_gather<<<((size_t)n_dst * 32 + 255) / 256, 256, 0, stream>>>(
                x, ns_blk + ns_base[r], offs, nd_base[r], sorted, n_dst, mbuf);

            float* stats = stats0 + (size_t)(l * 9 + r) * 256;
            int chunks = (n_dst + 31) / 32;
            int ggrid = chunks < 768 ? chunks : 768;
            k_gemm_stats<<<ggrid, 256, 0, stream>>>(
                mbuf, W + (size_t)(l * 9 + r) * D * D, nd_blk + nd_base[r], n_dst, stats);

            int mode = touched[dt] ? 1 : (l == 0 ? 0 : 2);
            float* dbuf = (l == 0) ? ws_feat[dt] : out_feat[dt];
            long total4 = (long)n_dst * (D / 4);
            int ngrid = (int)((total4 + 255) / 256);
            if (ngrid > 2048) ngrid = 2048;
            k_norm<<<ngrid, 256, 0, stream>>>(
                (const float4*)mbuf, stats,
                gamma + (size_t)(l * 9 + r) * D, beta + (size_t)(l * 9 + r) * D,
                1.0f / (float)n_dst, total4, (float4*)dbuf,
                (const float4*)feat_in[dt], mode);
            touched[dt] = true;
        }
    }
}

// Round 3
// 2284.534 us; speedup vs baseline: 3.7801x; 2.0356x over previous
//
#include <hip/hip_runtime.h>
#include <cstdint>

#define D 128

typedef __attribute__((ext_vector_type(8))) short short8;
typedef __attribute__((ext_vector_type(4))) float f32x4;

__device__ inline ushort f2bf(float f) {
    uint u = __float_as_uint(f);
    uint r = (u + 0x7fffu + ((u >> 16) & 1u)) >> 16;
    return (ushort)r;
}
__device__ inline float bf2f(ushort u) { return __uint_as_float(((uint)u) << 16); }

// ---------------------------------------------------------------- degree / CSR build

__global__ void k_count(const int* __restrict__ src, const int* __restrict__ dst,
                        int E, float* __restrict__ degs, float* __restrict__ degd) {
    int i = blockIdx.x * blockDim.x + threadIdx.x;
    if (i < E) {
        atomicAdd(&degs[src[i]], 1.0f);
        atomicAdd(&degd[dst[i]], 1.0f);
    }
}

__global__ void k_rsqrt(float* __restrict__ p, int n) {
    int i = blockIdx.x * blockDim.x + threadIdx.x;
    if (i < n) {
        float d = p[i];
        p[i] = d > 0.0f ? rsqrtf(d) : 0.0f;
    }
}

__global__ void k_scan1(const float* __restrict__ cnt, int* __restrict__ off,
                        int* __restrict__ bsum, int n) {
    __shared__ int s[256];
    int t = threadIdx.x, i = blockIdx.x * 256 + t;
    int v = (i < n) ? (int)cnt[i] : 0;
    int acc = v;
    s[t] = acc; __syncthreads();
    for (int d = 1; d < 256; d <<= 1) {
        int add = (t >= d) ? s[t - d] : 0;
        __syncthreads();
        acc += add; s[t] = acc; __syncthreads();
    }
    if (i < n) off[i] = acc - v;
    if (t == 255) bsum[blockIdx.x] = acc;
}

__global__ __launch_bounds__(1024) void k_scan2(int* __restrict__ bsum, int nb) {
    __shared__ int s[1024];
    int t = threadIdx.x;
    int i0 = t * 3;
    int v0 = (i0     < nb) ? bsum[i0]     : 0;
    int v1 = (i0 + 1 < nb) ? bsum[i0 + 1] : 0;
    int v2 = (i0 + 2 < nb) ? bsum[i0 + 2] : 0;
    int tot = v0 + v1 + v2;
    int acc = tot;
    s[t] = acc; __syncthreads();
    for (int d = 1; d < 1024; d <<= 1) {
        int add = (t >= d) ? s[t - d] : 0;
        __syncthreads();
        acc += add; s[t] = acc; __syncthreads();
    }
    int base = acc - tot;
    if (i0     < nb) bsum[i0]     = base;
    if (i0 + 1 < nb) bsum[i0 + 1] = base + v0;
    if (i0 + 2 < nb) bsum[i0 + 2] = base + v0 + v1;
}

__global__ void k_scan3(int* __restrict__ off, const int* __restrict__ bsum, int n) {
    int i = blockIdx.x * 256 + threadIdx.x;
    if (i < n) off[i] += bsum[blockIdx.x];
}

__global__ void k_fill(const int* __restrict__ src, const int* __restrict__ dst,
                       int E, int* __restrict__ offs, int* __restrict__ sorted) {
    int e = blockIdx.x * blockDim.x + threadIdx.x;
    if (e < E) {
        int pos = atomicAdd(&offs[dst[e]], 1);
        sorted[pos] = src[e];
    }
}

// W[18][128k][128n] fp32 -> Wt[18][128n][128k] bf16
__global__ void k_prepw(const float* __restrict__ W, ushort* __restrict__ Wt) {
    int i = blockIdx.x * 256 + threadIdx.x;
    if (i < 18 * 16384) {
        int r = i >> 14, j = i & 16383, nn = j >> 7, kk = j & 127;
        Wt[i] = f2bf(W[(r << 14) + (kk << 7) + nn]);
    }
}

// ---------------------------------------------------------------- gather (bf16 out, nd pre-scaled)

__device__ inline float4 loadx(const float* x, size_t idx) { return *(const float4*)(x + idx); }
__device__ inline float4 loadx(const ushort* x, size_t idx) {
    ushort4 u = *(const ushort4*)(x + idx);
    float4 v;
    v.x = bf2f(u.x); v.y = bf2f(u.y); v.z = bf2f(u.z); v.w = bf2f(u.w);
    return v;
}

template <typename XT>
__global__ void k_gather(const XT* __restrict__ x, const float* __restrict__ ns,
                         const float* __restrict__ nd,
                         const int* __restrict__ OFFS, int gdbase,
                         const int* __restrict__ sorted, int n_dst,
                         ushort* __restrict__ m) {
    int gid = blockIdx.x * blockDim.x + threadIdx.x;
    int row = gid >> 5;
    if (row >= n_dst) return;
    int c4 = (gid & 31) * 4;
    int gd = gdbase + row;
    int beg = (gd == 0) ? 0 : OFFS[gd - 1];
    int end = OFFS[gd];
    float4 acc = {0.f, 0.f, 0.f, 0.f};
    for (int j = beg; j < end; ++j) {
        int s = sorted[j];
        float w = ns[s];
        float4 v = loadx(x, ((size_t)s << 7) + c4);
        acc.x += v.x * w; acc.y += v.y * w; acc.z += v.z * w; acc.w += v.w * w;
    }
    float sc = nd[row];
    ushort4 o;
    o.x = f2bf(acc.x * sc); o.y = f2bf(acc.y * sc);
    o.z = f2bf(acc.z * sc); o.w = f2bf(acc.w * sc);
    *(ushort4*)(m + ((size_t)row << 7) + c4) = o;
}

// ---------------------------------------------------------------- MFMA GEMM + BN stats

// out[r][:] = m_bf16[r][:] @ W  (W given transposed bf16), stats += per-channel sum/sumsq.
// Block: 256 thr = 4 waves, 64 rows x 128 cols. K=128 in 4 steps of 32.
__global__ __launch_bounds__(256) void k_gemm_mfma(
    const ushort* __restrict__ mb, const ushort* __restrict__ Wt,
    int n, float* __restrict__ outp, float* __restrict__ stats) {
    __shared__ ushort Wl[128 * 136];  // padded +8: 2-way bank aliasing only
    __shared__ ushort Al[64 * 136];
    __shared__ float Sl[256];
    int t = threadIdx.x;
    int w = t >> 6, lane = t & 63, lm = lane & 15, lg = lane >> 4;
    int r0 = blockIdx.x * 64;
    Sl[t] = 0.0f;

    for (int i = t; i < 2048; i += 256) {          // Wt: 128x128 bf16
        int row = i >> 4, c8 = (i & 15) << 3;
        *(short8*)&Wl[row * 136 + c8] = *(const short8*)&Wt[(row << 7) + c8];
    }
    for (int i = t; i < 1024; i += 256) {          // A: 64 rows (zero-fill tail)
        int row = i >> 4, c8 = (i & 15) << 3;
        short8 v = {};
        if (r0 + row < n) v = *(const short8*)&mb[((size_t)(r0 + row) << 7) + c8];
        *(short8*)&Al[row * 136 + c8] = v;
    }
    __syncthreads();

    f32x4 acc[8] = {};
    int abase = (w * 16 + lm) * 136 + lg * 8;
    #pragma unroll
    for (int kb = 0; kb < 128; kb += 32) {
        short8 a = *(short8*)&Al[abase + kb];
        #pragma unroll
        for (int c = 0; c < 8; ++c) {
            short8 b = *(short8*)&Wl[(c * 16 + lm) * 136 + kb + lg * 8];
            acc[c] = __builtin_amdgcn_mfma_f32_16x16x32_bf16(a, b, acc[c], 0, 0, 0);
        }
    }

    // BN stats: lane's 4 values are 4 rows of channel c*16+lm
    #pragma unroll
    for (int c = 0; c < 8; ++c) {
        float s1 = acc[c][0] + acc[c][1] + acc[c][2] + acc[c][3];
        float s2 = acc[c][0] * acc[c][0] + acc[c][1] * acc[c][1]
                 + acc[c][2] * acc[c][2] + acc[c][3] * acc[c][3];
        s1 += __shfl_xor(s1, 16); s1 += __shfl_xor(s1, 32);
        s2 += __shfl_xor(s2, 16); s2 += __shfl_xor(s2, 32);
        if (lg == 0) {
            atomicAdd(&Sl[c * 16 + lm], s1);
            atomicAdd(&Sl[128 + c * 16 + lm], s2);
        }
    }

    #pragma unroll
    for (int i = 0; i < 4; ++i) {
        int row = r0 + w * 16 + lg * 4 + i;
        if (row < n) {
            #pragma unroll
            for (int c = 0; c < 8; ++c)
                outp[((size_t)row << 7) + c * 16 + lm] = acc[c][i];
        }
    }
    __syncthreads();
    atomicAdd(&stats[t], Sl[t]);
}

// ---------------------------------------------------------------- BN normalize

// fp32 dst. mode 1: dst += v; mode 2: dst = v + resid
__global__ void k_norm(const float4* __restrict__ out4, const float* __restrict__ stats,
                       const float* __restrict__ gamma, const float* __restrict__ beta,
                       float inv_n, int total4, float4* __restrict__ dst4,
                       const float4* __restrict__ resid4, int mode) {
    __shared__ float sc[128], sh[128];
    int t = threadIdx.x;
    if (t < 128) {
        float mu = stats[t] * inv_n;
        float var = stats[128 + t] * inv_n - mu * mu;
        float s = gamma[t] * rsqrtf(var + 1e-5f);
        sc[t] = s;
        sh[t] = beta[t] - mu * s;
    }
    __syncthreads();
    for (int i = blockIdx.x * blockDim.x + t; i < total4; i += gridDim.x * blockDim.x) {
        int c4 = (i & 31) * 4;
        float4 v = out4[i];
        float4 r;
        r.x = v.x * sc[c4 + 0] + sh[c4 + 0];
        r.y = v.y * sc[c4 + 1] + sh[c4 + 1];
        r.z = v.z * sc[c4 + 2] + sh[c4 + 2];
        r.w = v.w * sc[c4 + 3] + sh[c4 + 3];
        if (mode == 1) {
            float4 d = dst4[i];
            r.x += d.x; r.y += d.y; r.z += d.z; r.w += d.w;
        } else if (mode == 2) {
            float4 d = resid4[i];
            r.x += d.x; r.y += d.y; r.z += d.z; r.w += d.w;
        }
        dst4[i] = r;
    }
}

// bf16 dst. mode 0: dst = v; mode 1: dst += v
__global__ void k_norm_bf(const float4* __restrict__ out4, const float* __restrict__ stats,
                          const float* __restrict__ gamma, const float* __restrict__ beta,
                          float inv_n, int total4, ushort* __restrict__ dst, int mode) {
    __shared__ float sc[128], sh[128];
    int t = threadIdx.x;
    if (t < 128) {
        float mu = stats[t] * inv_n;
        float var = stats[128 + t] * inv_n - mu * mu;
        float s = gamma[t] * rsqrtf(var + 1e-5f);
        sc[t] = s;
        sh[t] = beta[t] - mu * s;
    }
    __syncthreads();
    for (int i = blockIdx.x * blockDim.x + t; i < total4; i += gridDim.x * blockDim.x) {
        int c4 = (i & 31) * 4;
        float4 v = out4[i];
        float4 r;
        r.x = v.x * sc[c4 + 0] + sh[c4 + 0];
        r.y = v.y * sc[c4 + 1] + sh[c4 + 1];
        r.z = v.z * sc[c4 + 2] + sh[c4 + 2];
        r.w = v.w * sc[c4 + 3] + sh[c4 + 3];
        if (mode == 1) {
            ushort4 d = *(const ushort4*)(dst + (size_t)i * 4);
            r.x += bf2f(d.x); r.y += bf2f(d.y); r.z += bf2f(d.z); r.w += bf2f(d.w);
        }
        ushort4 o;
        o.x = f2bf(r.x); o.y = f2bf(r.y); o.z = f2bf(r.z); o.w = f2bf(r.w);
        *(ushort4*)(dst + (size_t)i * 4) = o;
    }
}

// ---------------------------------------------------------------- launch

extern "C" void kernel_launch(void* const* d_in, const int* in_sizes, int n_in,
                              void* d_out, int out_size, void* d_ws, size_t ws_size,
                              hipStream_t stream) {
    static const int NT[3]   = {100000, 150000, 2000};
    static const int RE[9]   = {300000, 300000, 100000, 100000, 150000, 150000, 100000, 150000, 2000};
    static const int RSRC[9] = {0, 1, 0, 2, 1, 2, 0, 1, 2};
    static const int RDST[9] = {1, 0, 2, 0, 2, 1, 0, 1, 2};
    const int TOT_N = 756000;
    const int NB = (TOT_N + 255) / 256;

    const float* feat_in[3] = {(const float*)d_in[0], (const float*)d_in[1], (const float*)d_in[2]};
    const float* W     = (const float*)d_in[3];
    const float* gamma = (const float*)d_in[5];
    const float* beta  = (const float*)d_in[6];
    float* ws  = (float*)d_ws;
    float* out = (float*)d_out;

    int ns_base[9], nd_base[9];
    {
        int s = 0, d = 0;
        for (int r = 0; r < 9; ++r) {
            ns_base[r] = s; s += NT[RSRC[r]];
            nd_base[r] = d; d += NT[RDST[r]];
        }
    }

    // workspace layout (float units; bf16 buffers use half-count)
    const size_t H_A    = 0;                        // 100000*128 bf16
    const size_t H_B    = H_A + 6400000;            // 150000*128 bf16
    const size_t H_G    = H_B + 9600000;            // 2000*128 bf16
    const size_t MBUF   = H_G + 128000;             // 150000*128 bf16
    const size_t OUT    = MBUF + 9600000;           // 150000*128 fp32
    const size_t WT     = OUT + 19200000;           // 18*128*128 bf16
    const size_t STATS  = WT + 147456;              // 18*256 fp32
    const size_t NS     = STATS + 4608;             // 756000
    const size_t ND     = NS + 756000;              // 756000
    const size_t OFFS   = ND + 756000;              // 756000 ints
    const size_t SORTED = OFFS + 756000;            // 1352000 ints
    const size_t BSUM   = SORTED + 1352000;         // scan blocks

    ushort* h_feat[3] = {(ushort*)(ws + H_A), (ushort*)(ws + H_B), (ushort*)(ws + H_G)};
    float* out_feat[3] = {out, out + 12800000, out + 32000000};
    ushort* mbuf   = (ushort*)(ws + MBUF);
    float*  obuf   = ws + OUT;
    ushort* wt     = (ushort*)(ws + WT);
    float*  stats0 = ws + STATS;
    float*  ns_blk = ws + NS;
    float*  nd_blk = ws + ND;
    int*    offs   = (int*)(ws + OFFS);
    int*    sorted = (int*)(ws + SORTED);
    int*    bsum   = (int*)(ws + BSUM);

    // zero stats + degree counters (contiguous)
    hipMemsetAsync(ws + STATS, 0, (4608 + 2 * 756000) * sizeof(float), stream);

    for (int r = 0; r < 9; ++r) {
        const int* src = (const int*)d_in[7 + 2 * r];
        const int* dst = (const int*)d_in[8 + 2 * r];
        k_count<<<(RE[r] + 255) / 256, 256, 0, stream>>>(
            src, dst, RE[r], ns_blk + ns_base[r], nd_blk + nd_base[r]);
    }
    k_scan1<<<NB, 256, 0, stream>>>(nd_blk, offs, bsum, TOT_N);
    k_scan2<<<1, 1024, 0, stream>>>(bsum, NB);
    k_scan3<<<NB, 256, 0, stream>>>(offs, bsum, TOT_N);
    for (int r = 0; r < 9; ++r) {
        const int* src = (const int*)d_in[7 + 2 * r];
        const int* dst = (const int*)d_in[8 + 2 * r];
        k_fill<<<(RE[r] + 255) / 256, 256, 0, stream>>>(
            src, dst, RE[r], offs + nd_base[r], sorted);
    }
    k_rsqrt<<<(2 * TOT_N + 255) / 256, 256, 0, stream>>>(ns_blk, 2 * TOT_N);
    k_prepw<<<(18 * 16384 + 255) / 256, 256, 0, stream>>>(W, wt);

    for (int l = 0; l < 2; ++l) {
        bool touched[3] = {false, false, false};
        for (int r = 0; r < 9; ++r) {
            int st = RSRC[r], dt = RDST[r];
            int n_dst = NT[dt];

            if (l == 0)
                k_gather<float><<<((size_t)n_dst * 32 + 255) / 256, 256, 0, stream>>>(
                    feat_in[st], ns_blk + ns_base[r], nd_blk + nd_base[r],
                    offs, nd_base[r], sorted, n_dst, mbuf);
            else
                k_gather<ushort><<<((size_t)n_dst * 32 + 255) / 256, 256, 0, stream>>>(
                    h_feat[st], ns_blk + ns_base[r], nd_blk + nd_base[r],
                    offs, nd_base[r], sorted, n_dst, mbuf);

            float* stats = stats0 + (size_t)(l * 9 + r) * 256;
            k_gemm_mfma<<<(n_dst + 63) / 64, 256, 0, stream>>>(
                mbuf, wt + (size_t)(l * 9 + r) * 16384, n_dst, obuf, stats);

            int total4 = n_dst * 32;
            int ngrid = (total4 + 255) / 256;
            if (ngrid > 2048) ngrid = 2048;
            const float* g = gamma + (size_t)(l * 9 + r) * D;
            const float* b = beta  + (size_t)(l * 9 + r) * D;
            if (l == 0) {
                int mode = touched[dt] ? 1 : 0;
                k_norm_bf<<<ngrid, 256, 0, stream>>>(
                    (const float4*)obuf, stats, g, b, 1.0f / (float)n_dst,
                    total4, h_feat[dt], mode);
            } else {
                int mode = touched[dt] ? 1 : 2;
                k_norm<<<ngrid, 256, 0, stream>>>(
                    (const float4*)obuf, stats, g, b, 1.0f / (float)n_dst,
                    total4, (float4*)out_feat[dt], (const float4*)feat_in[dt], mode);
            }
            touched[dt] = true;
        }
    }
}